// Round 1
// 60896.143 us; speedup vs baseline: 1.9900x; 1.9900x over previous
//
#include <hip/hip_runtime.h>

// ELMo 2-layer LSTM-with-projection, persistent kernel for MI355X (gfx950).
// B=32, T=1024, H=512(=input), CELL=4096, gates=16384, K(fused)=1024.
//
// R3: LAYER PIPELINING. The kernel was serial-latency bound: 2048 dependent
// timesteps x ~51us of barrier+IF latency (MfmaUtil 0.9%). Layer 2 at time t
// depends only on layer 1 at time t, so the two layers now run CONCURRENTLY
// on disjoint grid halves: WGs 0..127 = layer 1, WGs 128..255 = layer 2,
// each group with its own 128-arrival barrier counter; layer 2 waits on
// layer 1's monotonic counter (l1 never waits on l2). 2048 -> ~1025 steps.
//
// To hold BOTH layers' [Wi;Ws] bf16 in registers (64MB chip-wide = exactly
// the VGPR capacity at 8 waves/CU x 128-reg fragments), WGs are 512 threads
// (8 waves; wave = gate x M-tile, 16 gate-rows each, wfrag[32]=128 VGPR)
// and cover the FULL batch N=32 (two N=16 MFMA halves staged through one
// 33KB xh buffer). 256 WGs = 1/CU: residency guaranteed as before.
// Projection partials go direct-to-global in [wg][n][p] layout (pbuf
// removed; LDS 57KB static); reduce does 8x8B loads/thread; running h kept
// in a register per owned column.

#define TT 1024
#define HH 512
#define CC 4096

typedef __bf16 bf16_t;
typedef __attribute__((ext_vector_type(8))) __bf16 bf16x8;
typedef __attribute__((ext_vector_type(4))) __bf16 bf16x4;
typedef __attribute__((ext_vector_type(4))) float f32x4;

#define OUT_FH 16777216u          // 32*1024*512
#define OUT_FC 16809984u          // + 2*32*512

__device__ __forceinline__ float fsigm(float x) { return 1.0f / (1.0f + __expf(-x)); }
__device__ __forceinline__ float ftanh(float x) {
  x = fminf(fmaxf(x, -15.f), 15.f);
  float e = __expf(2.f * x);
  return (e - 1.f) / (e + 1.f);
}

// Monotonic-counter barrier over one layer-group (128 WGs). Release fence
// before arrival; relaxed add; relaxed polls; one acquire fence after.
__device__ __forceinline__ void gridbar(unsigned* cnt, unsigned target) {
  __syncthreads();
  if (threadIdx.x == 0) {
    __builtin_amdgcn_fence(__ATOMIC_RELEASE, "agent");
    __hip_atomic_fetch_add(cnt, 1u, __ATOMIC_RELAXED, __HIP_MEMORY_SCOPE_AGENT);
    while (__hip_atomic_load(cnt, __ATOMIC_RELAXED, __HIP_MEMORY_SCOPE_AGENT) < target)
      __builtin_amdgcn_s_sleep(2);
    __builtin_amdgcn_fence(__ATOMIC_ACQUIRE, "agent");
  }
  __syncthreads();
}

__global__ void prep(const int* __restrict__ mask, int* __restrict__ len,
                     unsigned* __restrict__ cnt) {
  const int b = blockIdx.x, tid = threadIdx.x;
  int s = 0;
  for (int i = tid; i < TT; i += 256) s += mask[b * TT + i];
  __shared__ int r[256];
  r[tid] = s; __syncthreads();
  for (int st = 128; st > 0; st >>= 1) {
    if (tid < st) r[tid] += r[tid + st];
    __syncthreads();
  }
  if (tid == 0) { len[b] = r[0]; if (b == 0) { cnt[0] = 0u; cnt[16] = 0u; } }
}

__global__ __launch_bounds__(512, 2) void elmo_lstm(
    const float* __restrict__ xin,
    const float* __restrict__ Wi_g, const float* __restrict__ Ws_g,
    const float* __restrict__ bs_g, const float* __restrict__ Wp_g,
    float* __restrict__ out,
    unsigned* __restrict__ cnt, const int* __restrict__ len_g,
    bf16_t* __restrict__ P, bf16_t* __restrict__ hbuf) {
  const int g    = blockIdx.x;
  const int L    = g >> 7;        // layer (0: WGs 0..127, 1: WGs 128..255)
  const int wgi  = g & 127;
  const int cb   = wgi * 32;      // owned cell base
  const int tid  = threadIdx.x;
  const int wv   = tid >> 6;      // wave 0..7
  const int gate = wv >> 1;       // 0..3
  const int mt   = wv & 1;        // M-tile within gate (16 rows each)
  const int lane = tid & 63;
  const int lm   = lane & 15;
  const int lq   = lane >> 4;
  const int pb   = wgi * 4;       // owned h-column base (reduce phase)

  // xh[16][1032] bf16 (33,024B) union rbuf[32][16][4] f32 (8,192B):
  // xh dead after the GEMM halves; rbuf used only after gridbar #1.
  __shared__ __align__(16) char uA[33024];
  __shared__ float  gbuf[4][32][33];   // [gate][cell][n]
  __shared__ float  cbuf[32][33];      // persistent c-state [cell][n]
  __shared__ bf16_t abuf[32][48];      // act [n][cell]
  __shared__ int    lenl[32];

  bf16_t (*xh)[1032]   = (bf16_t(*)[1032])uA;
  float  (*rbuf)[16][4] = (float(*)[16][4])uA;

  if (tid < 32) lenl[tid] = len_g[tid];

  unsigned* mycnt = cnt + L * 16;      // own group's barrier counter
  unsigned* c1    = cnt;               // layer-1 group's counter (progress)

  const float* WiL = Wi_g + (size_t)L * CC * 4 * HH;
  const float* WsL = Ws_g + (size_t)L * CC * 4 * HH;
  const float* bsL = bs_g + (size_t)L * CC * 4;
  const float* WpL = Wp_g + (size_t)L * HH * CC;

  // ---- weights -> registers: gate A-fragments (16 rows x 1024 K per wave)
  bf16x8 wfrag[32];                    // 128 VGPRs
  {
    const int row = gate * CC + cb + mt * 16 + lm;
#pragma unroll
    for (int ks = 0; ks < 32; ++ks) {
      const int k = ks * 32 + lq * 8;
      const float* src = (k < HH) ? (WiL + (size_t)row * HH + k)
                                  : (WsL + (size_t)row * HH + (k - HH));
      float4 a = ((const float4*)src)[0];
      float4 b = ((const float4*)src)[1];
      bf16x8 f;
      f[0] = (bf16_t)a.x; f[1] = (bf16_t)a.y; f[2] = (bf16_t)a.z; f[3] = (bf16_t)a.w;
      f[4] = (bf16_t)b.x; f[5] = (bf16_t)b.y; f[6] = (bf16_t)b.z; f[7] = (bf16_t)b.w;
      wfrag[ks] = f;
    }
  }
  float biasv[4];
#pragma unroll
  for (int r = 0; r < 4; ++r)
    biasv[r] = bsL[gate * CC + cb + mt * 16 + lq * 4 + r];

  bf16x8 pfrag[4];                     // Wp rows wv*64+pt*16+lm, cols cb+lq*8
#pragma unroll
  for (int pt = 0; pt < 4; ++pt) {
    const float* src = WpL + (size_t)(wv * 64 + pt * 16 + lm) * CC + cb + lq * 8;
    float4 a = ((const float4*)src)[0];
    float4 b = ((const float4*)src)[1];
    bf16x8 f;
    f[0] = (bf16_t)a.x; f[1] = (bf16_t)a.y; f[2] = (bf16_t)a.z; f[3] = (bf16_t)a.w;
    f[4] = (bf16_t)b.x; f[5] = (bf16_t)b.y; f[6] = (bf16_t)b.z; f[7] = (bf16_t)b.w;
    pfrag[pt] = f;
  }

  // ---- state init ----
  for (int i = tid; i < 32 * 33; i += 512) (&cbuf[0][0])[i] = 0.f;
  bf16_t* hb = hbuf + (size_t)L * 32 * HH;
  if (tid < 128) {                     // zero owned h columns (all 32 batch rows)
    int n = tid >> 2, p = pb + (tid & 3);
    hb[(size_t)n * HH + p] = (bf16_t)0.f;
  }
  unsigned bark = 0;
  gridbar(mycnt, 128u * (++bark));

  const float* xsrc = (L == 0) ? xin : out;      // layer2 input = layer1 out
  bf16_t* Pl = P + (size_t)L * 128 * 32 * HH;    // own layer's partial buffer
  float hp = 0.f;                                // running h (tid<128 only)

#pragma unroll 1
  for (int t = 0; t < TT; ++t) {
    // ---- layer 2 waits for layer 1 step t completion (out[.,t,.] sealed) ----
    if (L == 1) {
      if (tid == 0) {
        const unsigned tgt = 128u * (2u * (unsigned)t + 3u);
        while (__hip_atomic_load(c1, __ATOMIC_RELAXED, __HIP_MEMORY_SCOPE_AGENT) < tgt)
          __builtin_amdgcn_s_sleep(2);
        __builtin_amdgcn_fence(__ATOMIC_ACQUIRE, "agent");
      }
      __syncthreads();
    }

    // ---- gate GEMM over two N=16 halves through one xh buffer ----
    f32x4 acc0, acc1;
#pragma unroll
    for (int nh = 0; nh < 2; ++nh) {
      {
        const int r = tid & 15, q = tid >> 4;    // wave-uniform x/h split
        const int n = nh * 16 + r;
        if (q < 16) {                            // x part: 32 fp32 -> bf16
          const int co = q * 32;
          const float* xs = xsrc + ((size_t)n * TT + t) * HH + co;
#pragma unroll
          for (int i = 0; i < 8; ++i) {
            float4 v = ((const float4*)xs)[i];
            bf16x4 pv = { (bf16_t)v.x, (bf16_t)v.y, (bf16_t)v.z, (bf16_t)v.w };
            *(bf16x4*)&xh[r][co + i * 4] = pv;
          }
        } else {                                 // h part: 32 bf16
          const int co = (q - 16) * 32;
          const int4* hs = (const int4*)(hb + (size_t)n * HH + co);
#pragma unroll
          for (int i = 0; i < 4; ++i)
            *(int4*)&xh[r][HH + co + i * 8] = hs[i];
        }
      }
      __syncthreads();
      f32x4 a = { biasv[0], biasv[1], biasv[2], biasv[3] };
#pragma unroll
      for (int ks = 0; ks < 32; ++ks) {
        bf16x8 bfr = *(const bf16x8*)&xh[lm][ks * 32 + lq * 8];
        a = __builtin_amdgcn_mfma_f32_16x16x32_bf16(wfrag[ks], bfr, a, 0, 0, 0);
      }
      if (nh == 0) acc0 = a; else acc1 = a;
      __syncthreads();                           // xh reads done before re-stage
    }

    // ---- gates -> LDS ----
    {
      const int crow = mt * 16;
#pragma unroll
      for (int r = 0; r < 4; ++r) {
        gbuf[gate][crow + lq * 4 + r][lm]      = acc0[r];
        gbuf[gate][crow + lq * 4 + r][16 + lm] = acc1[r];
      }
    }
    __syncthreads();

    // ---- elementwise LSTM cell (2 (cell,n) pairs / thread) ----
#pragma unroll
    for (int e = 0; e < 2; ++e) {
      const int pp = tid * 2 + e;
      const int cell = pp >> 5, n = pp & 31;
      float ig = gbuf[0][cell][n], fg = gbuf[1][cell][n];
      float mg = gbuf[2][cell][n], og = gbuf[3][cell][n];
      float iv = fsigm(ig), fv = fsigm(fg), gv = ftanh(mg), ov = fsigm(og);
      float cp = cbuf[cell][n];
      float c  = fminf(fmaxf(iv * gv + fv * cp, -3.f), 3.f);
      const bool valid = t < lenl[n];
      float cn = valid ? c : cp;
      cbuf[cell][n] = cn;
      abuf[n][cell] = (bf16_t)(ov * ftanh(c));
      if (t == lenl[n] - 1)
        out[OUT_FC + ((size_t)(L * 32 + n)) * CC + cb + cell] = cn;
    }
    __syncthreads();

    // ---- projection over own 32 cells: direct global stores, [wg][n][p] ----
    {
      bf16x8 b0 = *(const bf16x8*)&abuf[lm][lq * 8];
      bf16x8 b1 = *(const bf16x8*)&abuf[16 + lm][lq * 8];
#pragma unroll
      for (int pt = 0; pt < 4; ++pt) {
        f32x4 p0 = { 0.f, 0.f, 0.f, 0.f };
        f32x4 p1 = { 0.f, 0.f, 0.f, 0.f };
        p0 = __builtin_amdgcn_mfma_f32_16x16x32_bf16(pfrag[pt], b0, p0, 0, 0, 0);
        p1 = __builtin_amdgcn_mfma_f32_16x16x32_bf16(pfrag[pt], b1, p1, 0, 0, 0);
        const int prow = wv * 64 + pt * 16 + lq * 4;
        bf16x4 s0 = { (bf16_t)p0[0], (bf16_t)p0[1], (bf16_t)p0[2], (bf16_t)p0[3] };
        bf16x4 s1 = { (bf16_t)p1[0], (bf16_t)p1[1], (bf16_t)p1[2], (bf16_t)p1[3] };
        *(bf16x4*)&Pl[((size_t)(wgi * 32 + lm)      * HH) + prow] = s0;
        *(bf16x4*)&Pl[((size_t)(wgi * 32 + 16 + lm) * HH) + prow] = s1;
      }
    }
    gridbar(mycnt, 128u * (++bark));

    // ---- reduce 128 partials for owned 4 h-columns (8 x 8B loads/thread) ----
    {
      const int n = tid >> 4, s = tid & 15;
      f32x4 sum = { 0.f, 0.f, 0.f, 0.f };
#pragma unroll
      for (int w2 = s * 8; w2 < s * 8 + 8; ++w2) {
        bf16x4 v = *(const bf16x4*)&Pl[((size_t)(w2 * 32 + n) * HH) + pb];
        sum[0] += (float)v[0]; sum[1] += (float)v[1];
        sum[2] += (float)v[2]; sum[3] += (float)v[3];
      }
      *(f32x4*)&rbuf[n][s][0] = sum;
    }
    __syncthreads();
    if (tid < 128) {
      const int n = tid >> 2, pi = tid & 3, p = pb + pi;
      float h = 0.f;
#pragma unroll
      for (int s = 0; s < 16; ++s) h += rbuf[n][s][pi];
      h = fminf(fmaxf(h, -3.f), 3.f);
      const bool valid = t < lenl[n];
      float hn = valid ? h : hp;
      hb[(size_t)n * HH + p] = (bf16_t)hn;
      float outv = valid ? h : 0.f;
      size_t oi = ((size_t)n * TT + t) * HH + p;
      if (L == 0) out[oi] = outv;      // layer-1 sequence (layer-2 input)
      else        out[oi] += outv;     // residual: returned = l2_out + l1_out
      if (t == lenl[n] - 1)
        out[OUT_FH + ((size_t)(L * 32 + n)) * HH + p] = hn;
      hp = hn;
    }
    gridbar(mycnt, 128u * (++bark));
  }
}

extern "C" void kernel_launch(void* const* d_in, const int* in_sizes, int n_in,
                              void* d_out, int out_size, void* d_ws, size_t ws_size,
                              hipStream_t stream) {
  const float* xin = (const float*)d_in[0];
  const int*   mask = (const int*)d_in[1];
  const float* Wi  = (const float*)d_in[2];
  const float* Ws  = (const float*)d_in[3];
  const float* bs  = (const float*)d_in[4];
  const float* Wp  = (const float*)d_in[5];
  float* out = (float*)d_out;
  char* ws = (char*)d_ws;

  unsigned* cnt = (unsigned*)(ws);                       // 2 counters, 64B apart
  int* len      = (int*)(ws + 512);
  bf16_t* P    = (bf16_t*)(ws + 1024);                   // 2*128*32*512 bf16 = 8 MB
  bf16_t* hbuf = (bf16_t*)(ws + 1024 + (size_t)2 * 128 * 32 * 512 * 2);

  prep<<<32, 256, 0, stream>>>(mask, len, cnt);
  elmo_lstm<<<256, 512, 0, stream>>>(xin, Wi, Ws, bs, Wp, out, cnt, len, P, hbuf);
}

// Round 4
// 32464.072 us; speedup vs baseline: 3.7329x; 1.8758x over previous
//
#include <hip/hip_runtime.h>

// ELMo 2-layer LSTM-with-projection, persistent kernel for MI355X (gfx950).
// B=32, T=1024, H=512(=input), CELL=4096, gates=16384, K(fused)=1024.
//
// R6: bit-exact-R3 numerics on the R5 fenceless/pipelined structure.
// R5 passed returned+final_h but failed final_c: c is a 1024-step clipped
// integrator that accumulates rounding noise per-cell (h averages it away
// over the 4096-wide projection), and R5's only numeric deviation from the
// harness-verified R3 was the h-reduction order (16x8+16-chain vs R3's
// 4x32+4-chain). Restored R3's exact order: thread (n,pi,s) sums partials
// w2 = s*32..s*32+31 sequentially, then h = ((r0+r1)+r2)+r3. All other ops
// already bit-match R3 (same MFMA operand order, same ks chain, same bf16
// converts, same clip/mask), so the full state trajectory reproduces R3's
// passing run. final_c/final_h stores also moved to sc1 (MALL) stores.
//
// Fenceless coherence (R4/R5): no release/acquire fences anywhere (they
// cost full L2 wb + L1/L2 inv per barrier -> 34.6GB fetch, 62us/step in
// R3). All cross-WG data (P partials, hbuf, out row t, counters) moves via
// relaxed agent-scope atomics = global_load/store sc0 sc1 (direct to MALL,
// no cache maintenance). Release ordering: sc1 stores ack from the
// coherence point and __syncthreads drains vmcnt(0) before the arrival
// add. Barrier arrivals spread over 8 sub-counters (256B apart, 16 each);
// lanes 0..7 poll.
//
// Grid: WGs 0..127 = layer 1, 128..255 = layer 2 (layer pipelining, R3);
// 512 thr/WG, full batch N=32, both layers' [Wi;Ws] bf16 in VGPRs.

#define TT 1024
#define HH 512
#define CC 4096

typedef __bf16 bf16_t;
typedef __attribute__((ext_vector_type(8))) __bf16 bf16x8;
typedef __attribute__((ext_vector_type(4))) __bf16 bf16x4;
typedef __attribute__((ext_vector_type(2))) __bf16 bf16x2;
typedef __attribute__((ext_vector_type(4))) float f32x4;
typedef unsigned long long ull_t;

#define OUT_FH 16777216u          // 32*1024*512
#define OUT_FC 16809984u          // + 2*32*512

__device__ __forceinline__ float fsigm(float x) { return 1.0f / (1.0f + __expf(-x)); }
__device__ __forceinline__ float ftanh(float x) {
  x = fminf(fmaxf(x, -15.f), 15.f);
  float e = __expf(2.f * x);
  return (e - 1.f) / (e + 1.f);
}

// Device-coherent (MALL) accessors: relaxed agent atomics -> sc0 sc1, no fences.
__device__ __forceinline__ void st_ull(void* p, ull_t v) {
  __hip_atomic_store((ull_t*)p, v, __ATOMIC_RELAXED, __HIP_MEMORY_SCOPE_AGENT);
}
__device__ __forceinline__ ull_t ld_ull(const void* p) {
  return __hip_atomic_load((const ull_t*)p, __ATOMIC_RELAXED, __HIP_MEMORY_SCOPE_AGENT);
}
__device__ __forceinline__ void st_f32(float* p, float v) {
  __hip_atomic_store(p, v, __ATOMIC_RELAXED, __HIP_MEMORY_SCOPE_AGENT);
}
__device__ __forceinline__ float ld_f32(const float* p) {
  return __hip_atomic_load(p, __ATOMIC_RELAXED, __HIP_MEMORY_SCOPE_AGENT);
}
__device__ __forceinline__ void st_u16(void* p, unsigned short v) {
  __hip_atomic_store((unsigned short*)p, v, __ATOMIC_RELAXED, __HIP_MEMORY_SCOPE_AGENT);
}
__device__ __forceinline__ unsigned short ld_u16(const void* p) {
  return __hip_atomic_load((const unsigned short*)p, __ATOMIC_RELAXED,
                           __HIP_MEMORY_SCOPE_AGENT);
}

// Fenceless grid barrier over one layer-group (128 WGs). __syncthreads drains
// each wave's sc1 stores (vmcnt(0) => acked at MALL); arrivals spread over
// 8 sub-counters (64-uint = 256B apart; wgi&7 -> 16 arrivals each).
__device__ __forceinline__ void gridbar(unsigned* base, int wgi, unsigned bark) {
  __syncthreads();
  if (threadIdx.x == 0)
    __hip_atomic_fetch_add(base + (wgi & 7) * 64, 1u, __ATOMIC_RELAXED,
                           __HIP_MEMORY_SCOPE_AGENT);
  if (threadIdx.x < 8) {
    const unsigned tgt = 16u * bark;
    while (__hip_atomic_load(base + threadIdx.x * 64, __ATOMIC_RELAXED,
                             __HIP_MEMORY_SCOPE_AGENT) < tgt)
      __builtin_amdgcn_s_sleep(1);
  }
  __syncthreads();
}

__global__ void prep(const int* __restrict__ mask, int* __restrict__ len,
                     unsigned* __restrict__ cnt) {
  const int b = blockIdx.x, tid = threadIdx.x;
  if (b == 0)
    for (int i = tid; i < 1024; i += 256)
      __hip_atomic_store(cnt + i, 0u, __ATOMIC_RELAXED, __HIP_MEMORY_SCOPE_AGENT);
  int s = 0;
  for (int i = tid; i < TT; i += 256) s += mask[b * TT + i];
  __shared__ int r[256];
  r[tid] = s; __syncthreads();
  for (int st = 128; st > 0; st >>= 1) {
    if (tid < st) r[tid] += r[tid + st];
    __syncthreads();
  }
  if (tid == 0) len[b] = r[0];
}

__global__ __launch_bounds__(512, 2) void elmo_lstm(
    const float* __restrict__ xin,
    const float* __restrict__ Wi_g, const float* __restrict__ Ws_g,
    const float* __restrict__ bs_g, const float* __restrict__ Wp_g,
    float* __restrict__ out,
    unsigned* __restrict__ cnt, const int* __restrict__ len_g,
    bf16_t* __restrict__ P, bf16_t* __restrict__ hbuf) {
  const int g    = blockIdx.x;
  const int L    = g >> 7;        // layer (0: WGs 0..127, 1: WGs 128..255)
  const int wgi  = g & 127;
  const int cb   = wgi * 32;      // owned cell base
  const int tid  = threadIdx.x;
  const int wv   = tid >> 6;      // wave 0..7
  const int gate = wv >> 1;       // 0..3
  const int mt   = wv & 1;        // M-tile within gate (16 rows each)
  const int lane = tid & 63;
  const int lm   = lane & 15;
  const int lq   = lane >> 4;
  const int pb   = wgi * 4;       // owned h-column base (reduce phase)

  // xh[16][1032] bf16 (33,024B) union rbuf[32][4][4] f32 (2,048B).
  __shared__ __align__(16) char uA[33024];
  __shared__ float  gbuf[4][32][33];   // [gate][cell][n]
  __shared__ float  cbuf[32][33];      // persistent c-state [cell][n]
  __shared__ bf16_t abuf[32][48];      // act [n][cell]
  __shared__ int    lenl[32];

  bf16_t (*xh)[1032]   = (bf16_t(*)[1032])uA;
  float  (*rbuf)[4][4] = (float(*)[4][4])uA;   // [n][pi][s]

  if (tid < 32) lenl[tid] = len_g[tid];

  unsigned* myc = cnt + L * 512;       // own group's 8 sub-counters
  unsigned* c1  = cnt;                 // layer-1 group's sub-counters

  const float* WiL = Wi_g + (size_t)L * CC * 4 * HH;
  const float* WsL = Ws_g + (size_t)L * CC * 4 * HH;
  const float* bsL = bs_g + (size_t)L * CC * 4;
  const float* WpL = Wp_g + (size_t)L * HH * CC;

  // ---- weights -> registers: gate A-fragments (16 rows x 1024 K per wave)
  bf16x8 wfrag[32];                    // 128 VGPRs
  {
    const int row = gate * CC + cb + mt * 16 + lm;
#pragma unroll
    for (int ks = 0; ks < 32; ++ks) {
      const int k = ks * 32 + lq * 8;
      const float* src = (k < HH) ? (WiL + (size_t)row * HH + k)
                                  : (WsL + (size_t)row * HH + (k - HH));
      float4 a = ((const float4*)src)[0];
      float4 b = ((const float4*)src)[1];
      bf16x8 f;
      f[0] = (bf16_t)a.x; f[1] = (bf16_t)a.y; f[2] = (bf16_t)a.z; f[3] = (bf16_t)a.w;
      f[4] = (bf16_t)b.x; f[5] = (bf16_t)b.y; f[6] = (bf16_t)b.z; f[7] = (bf16_t)b.w;
      wfrag[ks] = f;
    }
  }
  float biasv[4];
#pragma unroll
  for (int r = 0; r < 4; ++r)
    biasv[r] = bsL[gate * CC + cb + mt * 16 + lq * 4 + r];

  bf16x8 pfrag[4];                     // Wp rows wv*64+pt*16+lm, cols cb+lq*8
#pragma unroll
  for (int pt = 0; pt < 4; ++pt) {
    const float* src = WpL + (size_t)(wv * 64 + pt * 16 + lm) * CC + cb + lq * 8;
    float4 a = ((const float4*)src)[0];
    float4 b = ((const float4*)src)[1];
    bf16x8 f;
    f[0] = (bf16_t)a.x; f[1] = (bf16_t)a.y; f[2] = (bf16_t)a.z; f[3] = (bf16_t)a.w;
    f[4] = (bf16_t)b.x; f[5] = (bf16_t)b.y; f[6] = (bf16_t)b.z; f[7] = (bf16_t)b.w;
    pfrag[pt] = f;
  }

  // ---- state init ----
  for (int i = tid; i < 32 * 33; i += 512) (&cbuf[0][0])[i] = 0.f;
  bf16_t* hb = hbuf + (size_t)L * 32 * HH;
  if (tid < 128) {                     // zero owned h columns (all 32 batch rows)
    int n = tid >> 2, p = pb + (tid & 3);
    st_u16(hb + (size_t)n * HH + p, 0);
  }
  unsigned bark = 0;
  gridbar(myc, wgi, ++bark);

  const float* xsrc = (L == 0) ? xin : out;      // layer2 input = layer1 out
  bf16_t* Pl = P + (size_t)L * 128 * 32 * HH;    // own layer's partial buffer
  float hp = 0.f;                                // running h (tid<128 only)

#pragma unroll 1
  for (int t = 0; t < TT; ++t) {
    // ---- layer 2 waits for layer 1 step t completion (out row t sealed) ----
    if (L == 1) {
      if (tid < 8) {
        const unsigned tgt = 16u * (2u * (unsigned)t + 3u);
        while (__hip_atomic_load(c1 + tid * 64, __ATOMIC_RELAXED,
                                 __HIP_MEMORY_SCOPE_AGENT) < tgt)
          __builtin_amdgcn_s_sleep(1);
      }
      __syncthreads();
    }

    // ---- gate GEMM over two N=16 halves through one xh buffer ----
    f32x4 acc0, acc1;
#pragma unroll
    for (int nh = 0; nh < 2; ++nh) {
      {
        const int r = tid & 15, q = tid >> 4;    // wave-uniform x/h split
        const int n = nh * 16 + r;
        if (q < 16) {                            // x part: 32 fp32 -> bf16
          const int co = q * 32;
          const float* xs = xsrc + ((size_t)n * TT + t) * HH + co;
          if (L == 0) {                          // immutable input: cached loads
#pragma unroll
            for (int i = 0; i < 8; ++i) {
              float4 v = ((const float4*)xs)[i];
              bf16x4 pv = { (bf16_t)v.x, (bf16_t)v.y, (bf16_t)v.z, (bf16_t)v.w };
              *(bf16x4*)&xh[r][co + i * 4] = pv;
            }
          } else {                               // layer-1 product: MALL loads
            const ull_t* xu = (const ull_t*)xs;
#pragma unroll
            for (int i = 0; i < 16; ++i) {
              float2 v = __builtin_bit_cast(float2, ld_ull(xu + i));
              bf16x2 pv = { (bf16_t)v.x, (bf16_t)v.y };
              *(bf16x2*)&xh[r][co + i * 2] = pv;
            }
          }
        } else {                                 // h part: 32 bf16 (MALL loads)
          const int co = (q - 16) * 32;
          const ull_t* hs = (const ull_t*)(hb + (size_t)n * HH + co);
#pragma unroll
          for (int i = 0; i < 8; ++i)            // 8 x 8B = 32 bf16
            *(ull_t*)&xh[r][HH + co + i * 4] = ld_ull(hs + i);
        }
      }
      __syncthreads();
      f32x4 a = { biasv[0], biasv[1], biasv[2], biasv[3] };
#pragma unroll
      for (int ks = 0; ks < 32; ++ks) {
        bf16x8 bfr = *(const bf16x8*)&xh[lm][ks * 32 + lq * 8];
        a = __builtin_amdgcn_mfma_f32_16x16x32_bf16(wfrag[ks], bfr, a, 0, 0, 0);
      }
      if (nh == 0) acc0 = a; else acc1 = a;
      __syncthreads();                           // xh reads done before re-stage
    }

    // ---- gates -> LDS ----
    {
      const int crow = mt * 16;
#pragma unroll
      for (int r = 0; r < 4; ++r) {
        gbuf[gate][crow + lq * 4 + r][lm]      = acc0[r];
        gbuf[gate][crow + lq * 4 + r][16 + lm] = acc1[r];
      }
    }
    __syncthreads();

    // ---- elementwise LSTM cell (2 (cell,n) pairs / thread) ----
#pragma unroll
    for (int e = 0; e < 2; ++e) {
      const int pp = tid * 2 + e;
      const int cell = pp >> 5, n = pp & 31;
      float ig = gbuf[0][cell][n], fg = gbuf[1][cell][n];
      float mg = gbuf[2][cell][n], og = gbuf[3][cell][n];
      float iv = fsigm(ig), fv = fsigm(fg), gv = ftanh(mg), ov = fsigm(og);
      float cp = cbuf[cell][n];
      float c  = fminf(fmaxf(iv * gv + fv * cp, -3.f), 3.f);
      const bool valid = t < lenl[n];
      float cn = valid ? c : cp;
      cbuf[cell][n] = cn;
      abuf[n][cell] = (bf16_t)(ov * ftanh(c));
      if (t == lenl[n] - 1)
        st_f32(out + OUT_FC + ((size_t)(L * 32 + n)) * CC + cb + cell, cn);
    }
    __syncthreads();

    // ---- projection over own 32 cells: MALL-coherent stores, [wg][n][p] ----
    {
      bf16x8 b0 = *(const bf16x8*)&abuf[lm][lq * 8];
      bf16x8 b1 = *(const bf16x8*)&abuf[16 + lm][lq * 8];
#pragma unroll
      for (int pt = 0; pt < 4; ++pt) {
        f32x4 p0 = { 0.f, 0.f, 0.f, 0.f };
        f32x4 p1 = { 0.f, 0.f, 0.f, 0.f };
        p0 = __builtin_amdgcn_mfma_f32_16x16x32_bf16(pfrag[pt], b0, p0, 0, 0, 0);
        p1 = __builtin_amdgcn_mfma_f32_16x16x32_bf16(pfrag[pt], b1, p1, 0, 0, 0);
        const int prow = wv * 64 + pt * 16 + lq * 4;
        bf16x4 s0 = { (bf16_t)p0[0], (bf16_t)p0[1], (bf16_t)p0[2], (bf16_t)p0[3] };
        bf16x4 s1 = { (bf16_t)p1[0], (bf16_t)p1[1], (bf16_t)p1[2], (bf16_t)p1[3] };
        st_ull(&Pl[((size_t)(wgi * 32 + lm)      * HH) + prow],
               __builtin_bit_cast(ull_t, s0));
        st_ull(&Pl[((size_t)(wgi * 32 + 16 + lm) * HH) + prow],
               __builtin_bit_cast(ull_t, s1));
      }
    }
    gridbar(myc, wgi, ++bark);

    // ---- reduce: EXACT R3 arithmetic — thread (n,pi,s) sums partials
    //      w2 = s*32..s*32+31 sequentially; final ((r0+r1)+r2)+r3 ----
    {
      const int n = tid >> 4, pi = (tid >> 2) & 3, s = tid & 3;
      float sum = 0.f;
#pragma unroll 8
      for (int w2 = s * 32; w2 < s * 32 + 32; ++w2) {
        union { unsigned short u; bf16_t b; } cv;
        cv.u = ld_u16(&Pl[((size_t)(w2 * 32 + n)) * HH + pb + pi]);
        sum += (float)cv.b;
      }
      rbuf[n][pi][s] = sum;
    }
    __syncthreads();
    if (tid < 128) {
      const int n = tid >> 2, pi = tid & 3, p = pb + pi;
      float h = rbuf[n][pi][0] + rbuf[n][pi][1] + rbuf[n][pi][2] + rbuf[n][pi][3];
      h = fminf(fmaxf(h, -3.f), 3.f);
      const bool valid = t < lenl[n];
      float hn = valid ? h : hp;
      union { bf16_t b; unsigned short u; } hu; hu.b = (bf16_t)hn;
      st_u16(hb + (size_t)n * HH + p, hu.u);
      float outv = valid ? h : 0.f;
      size_t oi = ((size_t)n * TT + t) * HH + p;
      if (L == 0) {
        st_f32(out + oi, outv);            // seal row t at MALL for layer 2
      } else {
        float prev = ld_f32(out + oi);     // sealed L1 value via MALL
        out[oi] = prev + outv;             // residual; final, host-read only
      }
      if (t == lenl[n] - 1)
        st_f32(out + OUT_FH + ((size_t)(L * 32 + n)) * HH + p, hn);
      hp = hn;
    }
    gridbar(myc, wgi, ++bark);
  }
}

extern "C" void kernel_launch(void* const* d_in, const int* in_sizes, int n_in,
                              void* d_out, int out_size, void* d_ws, size_t ws_size,
                              hipStream_t stream) {
  const float* xin = (const float*)d_in[0];
  const int*   mask = (const int*)d_in[1];
  const float* Wi  = (const float*)d_in[2];
  const float* Ws  = (const float*)d_in[3];
  const float* bs  = (const float*)d_in[4];
  const float* Wp  = (const float*)d_in[5];
  float* out = (float*)d_out;
  char* ws = (char*)d_ws;

  unsigned* cnt = (unsigned*)ws;                 // 2 groups x 8 subcnt x 256B = 4KB
  int* len      = (int*)(ws + 4096);
  bf16_t* P    = (bf16_t*)(ws + 8192);           // 2*128*32*512 bf16 = 8 MB
  bf16_t* hbuf = (bf16_t*)(ws + 8192 + (size_t)2 * 128 * 32 * 512 * 2);

  prep<<<32, 256, 0, stream>>>(mask, len, cnt);
  elmo_lstm<<<256, 512, 0, stream>>>(xin, Wi, Ws, bs, Wp, out, cnt, len, P, hbuf);
}